// Round 1
// baseline (408.290 us; speedup 1.0000x reference)
//
#include <hip/hip_runtime.h>
#include <hip/hip_bf16.h>

#define TEMP_INV 20.0f
#define BATCH    1024
#define NSAMP    100000
#define NFEAT    256
#define BM       128
#define BN       128
#define BK       64
#define NCH      ((NSAMP + BN - 1) / BN)   /* 782 */
#define NCH_PAD  784                        /* 8 * 98 */
#define LDK      (BK + 8)                   /* padded LDS row stride (elems) */

typedef __bf16 bf16x8 __attribute__((ext_vector_type(8)));
typedef float  f32x4  __attribute__((ext_vector_type(4)));

#define NEG_SENTINEL (-1e30f)

// ---------------------------------------------------------------------------
// Kernel 1: per-row target logit in full fp32. One wave per row.
// grid 256 blocks x 256 threads (4 waves/block)
// ---------------------------------------------------------------------------
__global__ __launch_bounds__(256) void target_kernel(
    const float* __restrict__ inputs, const int* __restrict__ targets,
    const float* __restrict__ feats, float* __restrict__ tlogit)
{
    int lane = threadIdx.x & 63;
    int wid  = threadIdx.x >> 6;
    int row  = blockIdx.x * 4 + wid;           // 0..1023
    int tgt  = targets[row];
    const float4* a = (const float4*)(inputs + (size_t)row * NFEAT);
    const float4* f = (const float4*)(feats  + (size_t)tgt * NFEAT);
    float4 av = a[lane];
    float4 fv = f[lane];
    float d = av.x * fv.x + av.y * fv.y + av.z * fv.z + av.w * fv.w;
    #pragma unroll
    for (int off = 1; off < 64; off <<= 1)
        d += __shfl_xor(d, off, 64);
    if (lane == 0) tlogit[row] = d * TEMP_INV;
}

// ---------------------------------------------------------------------------
// Kernel 2: fused bf16 MFMA GEMM + per-chunk online-softmax partials.
// 128x128 tile, BK=64, 256 threads = 4 waves (2x2 of 64x64 wave tiles).
// partials layout: float2 [NCH][BATCH]  (coalesced writes)
// ---------------------------------------------------------------------------
__global__ __launch_bounds__(256) void gemm_softmax_kernel(
    const float* __restrict__ inputs, const float* __restrict__ feats,
    float2* __restrict__ partials)
{
    // XCD swizzle: all 8 m-tiles sharing an n-chunk get ids congruent mod 8
    int L  = blockIdx.x;            // 0 .. 8*NCH_PAD-1
    int j  = L & 7;
    int t  = L >> 3;
    int mx = t & 7;                 // m-tile 0..7
    int ny = (t >> 3) * 8 + j;      // n-chunk 0..783
    if (ny >= NCH) return;
    int m0 = mx * BM;
    int n0 = ny * BN;

    __shared__ __bf16 Alds[BM][LDK];
    __shared__ __bf16 Blds[BN][LDK];
    __shared__ float2 red[2][BM];

    int tid  = threadIdx.x;
    int lane = tid & 63;
    int wid  = tid >> 6;
    int wm   = wid & 1;             // wave row (0/1)
    int wn   = wid >> 1;            // wave col (0/1)
    int lrow = lane & 15;           // row(A)/col(B) within 16
    int quad = lane >> 4;           // k-group

    f32x4 acc[4][4] = {};

    // staging: thread covers 1 row, 32 consecutive k (of 64)
    int srow  = tid >> 1;           // 0..127
    int shalf = tid & 1;            // k offset 32*shalf
    const float* Aptr = inputs + (size_t)(m0 + srow) * NFEAT + shalf * 32;
    int brow = n0 + srow;
    const float* Bptr = feats + (size_t)brow * NFEAT + shalf * 32;
    bool bvalid = brow < NSAMP;

    for (int k0 = 0; k0 < NFEAT; k0 += BK) {
        float4 av[8], bv[8];
        #pragma unroll
        for (int i = 0; i < 8; i++)
            av[i] = ((const float4*)(Aptr + k0))[i];
        #pragma unroll
        for (int i = 0; i < 8; i++) {
            if (bvalid) bv[i] = ((const float4*)(Bptr + k0))[i];
            else        bv[i] = make_float4(0.f, 0.f, 0.f, 0.f);
        }
        __syncthreads();   // previous iter's LDS reads done
        #pragma unroll
        for (int i = 0; i < 4; i++) {
            bf16x8 pa, pb;
            float4 a0 = av[2 * i], a1 = av[2 * i + 1];
            float4 b0 = bv[2 * i], b1 = bv[2 * i + 1];
            pa[0] = (__bf16)a0.x; pa[1] = (__bf16)a0.y; pa[2] = (__bf16)a0.z; pa[3] = (__bf16)a0.w;
            pa[4] = (__bf16)a1.x; pa[5] = (__bf16)a1.y; pa[6] = (__bf16)a1.z; pa[7] = (__bf16)a1.w;
            pb[0] = (__bf16)b0.x; pb[1] = (__bf16)b0.y; pb[2] = (__bf16)b0.z; pb[3] = (__bf16)b0.w;
            pb[4] = (__bf16)b1.x; pb[5] = (__bf16)b1.y; pb[6] = (__bf16)b1.z; pb[7] = (__bf16)b1.w;
            *(bf16x8*)&Alds[srow][shalf * 32 + 8 * i] = pa;
            *(bf16x8*)&Blds[srow][shalf * 32 + 8 * i] = pb;
        }
        __syncthreads();
        #pragma unroll
        for (int ks = 0; ks < 2; ks++) {
            bf16x8 af[4], bf[4];
            #pragma unroll
            for (int mi = 0; mi < 4; mi++)
                af[mi] = *(bf16x8*)&Alds[wm * 64 + mi * 16 + lrow][ks * 32 + quad * 8];
            #pragma unroll
            for (int ni = 0; ni < 4; ni++)
                bf[ni] = *(bf16x8*)&Blds[wn * 64 + ni * 16 + lrow][ks * 32 + quad * 8];
            #pragma unroll
            for (int mi = 0; mi < 4; mi++)
                #pragma unroll
                for (int ni = 0; ni < 4; ni++)
                    acc[mi][ni] = __builtin_amdgcn_mfma_f32_16x16x32_bf16(
                        af[mi], bf[ni], acc[mi][ni], 0, 0, 0);
        }
    }

    // ---- epilogue: per-row (m, s) over this block's 128 columns ----
    // C layout: row = quad*4 + reg, col = lane&15 (within each 16x16 tile)
    int colbase = n0 + wn * 64 + lrow;
    #pragma unroll
    for (int mi = 0; mi < 4; mi++) {
        #pragma unroll
        for (int reg = 0; reg < 4; reg++) {
            float v[4];
            float m = NEG_SENTINEL;
            #pragma unroll
            for (int ni = 0; ni < 4; ni++) {
                bool ok = (colbase + ni * 16) < NSAMP;
                v[ni] = ok ? acc[mi][ni][reg] * TEMP_INV : NEG_SENTINEL;
                m = fmaxf(m, v[ni]);
            }
            float s = 0.f;
            #pragma unroll
            for (int ni = 0; ni < 4; ni++)
                s += __expf(v[ni] - m);
            // butterfly over the 16 column lanes (low 4 lane bits)
            #pragma unroll
            for (int off = 1; off < 16; off <<= 1) {
                float om = __shfl_xor(m, off, 64);
                float os = __shfl_xor(s, off, 64);
                float nm = fmaxf(m, om);
                s = s * __expf(m - nm) + os * __expf(om - nm);
                m = nm;
            }
            if (lrow == 0)
                red[wn][wm * 64 + mi * 16 + quad * 4 + reg] = make_float2(m, s);
        }
    }
    __syncthreads();
    if (tid < BM) {
        float2 a = red[0][tid], b = red[1][tid];
        float nm = fmaxf(a.x, b.x);
        float s  = a.y * __expf(a.x - nm) + b.y * __expf(b.x - nm);
        partials[(size_t)ny * BATCH + (m0 + tid)] = make_float2(nm, s);
    }
}

// ---------------------------------------------------------------------------
// Kernel 3: combine per-chunk partials -> lse -> nll -> mean (atomicAdd).
// grid 32 blocks x 256 threads; block handles 32 rows x 8 chunk-splits.
// ---------------------------------------------------------------------------
__global__ __launch_bounds__(256) void reduce_kernel(
    const float2* __restrict__ partials, const float* __restrict__ tlogit,
    float* __restrict__ out)
{
    __shared__ float2 red2[8][32];
    int tid = threadIdx.x;
    int rl  = tid & 31;
    int sp  = tid >> 5;
    int row = blockIdx.x * 32 + rl;
    int cs  = sp * 98;
    int ce  = cs + 98 < NCH ? cs + 98 : NCH;
    float m = NEG_SENTINEL, s = 0.f;
    #pragma unroll 4
    for (int c = cs; c < ce; c++) {
        float2 p = partials[(size_t)c * BATCH + row];
        float nm = fmaxf(m, p.x);
        s = s * __expf(m - nm) + p.y * __expf(p.x - nm);
        m = nm;
    }
    red2[sp][rl] = make_float2(m, s);
    __syncthreads();
    if (tid < 32) {
        float2 a = red2[0][rl];
        float M = a.x, S = a.y;
        #pragma unroll
        for (int q = 1; q < 8; q++) {
            float2 b = red2[q][rl];
            float nm = fmaxf(M, b.x);
            S = S * __expf(M - nm) + b.y * __expf(b.x - nm);
            M = nm;
        }
        float nll = (M + logf(S)) - tlogit[row];
        #pragma unroll
        for (int off = 1; off < 32; off <<= 1)
            nll += __shfl_xor(nll, off, 64);
        if (rl == 0) atomicAdd(out, nll * (1.0f / BATCH));
    }
}

// ---------------------------------------------------------------------------
extern "C" void kernel_launch(void* const* d_in, const int* in_sizes, int n_in,
                              void* d_out, int out_size, void* d_ws, size_t ws_size,
                              hipStream_t stream) {
    const float* inputs  = (const float*)d_in[0];
    const int*   targets = (const int*)d_in[1];
    const float* feats   = (const float*)d_in[2];
    float* out = (float*)d_out;

    float2* partials = (float2*)d_ws;
    float*  tlogit   = (float*)((char*)d_ws + sizeof(float2) * (size_t)NCH * BATCH);

    hipMemsetAsync(out, 0, sizeof(float), stream);
    target_kernel<<<BATCH / 4, 256, 0, stream>>>(inputs, targets, feats, tlogit);
    gemm_softmax_kernel<<<8 * NCH_PAD, 256, 0, stream>>>(inputs, feats, partials);
    reduce_kernel<<<BATCH / 32, 256, 0, stream>>>(partials, tlogit, out);
}

// Round 2
// 274.217 us; speedup vs baseline: 1.4889x; 1.4889x over previous
//
#include <hip/hip_runtime.h>
#include <hip/hip_bf16.h>

#define TEMP_INV 20.0f
#define BATCH    1024
#define NSAMP    100000
#define NFEAT    256
#define BM       128
#define BN       128
#define BK       64
#define NCH      ((NSAMP + BN - 1) / BN)   /* 782 */
#define NCH_PAD  784                        /* 8 * 98 */
#define NROWS_PAD (NCH * BN)                /* 100096 */

typedef __bf16 bf16x8 __attribute__((ext_vector_type(8)));
typedef float  f32x4  __attribute__((ext_vector_type(4)));

#define NEG_SENTINEL (-1e30f)

// async global->LDS, 16B per lane; LDS dest = wave-uniform base + lane*16
#define GLOAD_LDS16(g, l) __builtin_amdgcn_global_load_lds(               \
    (const __attribute__((address_space(1))) void*)(g),                   \
    (__attribute__((address_space(3))) void*)(l), 16, 0, 0)

// ---------------------------------------------------------------------------
// Kernel 0: convert feats (+zero-pad to 100096 rows) and inputs to bf16.
// One unit = 8 elems. feats units: 100096*256/8 = 3203072 (src 3200000),
// inputs units: 32768. total 3235840 = 12640 * 256.
// ---------------------------------------------------------------------------
#define FEAT_UNITS     3203072
#define FEAT_SRC_UNITS 3200000
#define CVT_UNITS      3235840
__global__ __launch_bounds__(256) void convert_kernel(
    const float* __restrict__ feats, const float* __restrict__ inputs,
    __bf16* __restrict__ fb, __bf16* __restrict__ ib)
{
    size_t u = (size_t)blockIdx.x * 256 + threadIdx.x;
    const float* src;
    __bf16* dst;
    bool zero = false;
    if (u < FEAT_UNITS) {
        dst = fb + u * 8;
        src = feats + u * 8;
        if (u >= FEAT_SRC_UNITS) zero = true;
    } else {
        size_t v = u - FEAT_UNITS;
        dst = ib + v * 8;
        src = inputs + v * 8;
    }
    bf16x8 o;
    if (!zero) {
        float4 a = ((const float4*)src)[0];
        float4 b = ((const float4*)src)[1];
        o[0] = (__bf16)a.x; o[1] = (__bf16)a.y; o[2] = (__bf16)a.z; o[3] = (__bf16)a.w;
        o[4] = (__bf16)b.x; o[5] = (__bf16)b.y; o[6] = (__bf16)b.z; o[7] = (__bf16)b.w;
    } else {
        #pragma unroll
        for (int i = 0; i < 8; i++) o[i] = (__bf16)0.0f;
    }
    *(bf16x8*)dst = o;
}

// ---------------------------------------------------------------------------
// Kernel 1: per-row target logit in full fp32. One wave per row.
// ---------------------------------------------------------------------------
__global__ __launch_bounds__(256) void target_kernel(
    const float* __restrict__ inputs, const int* __restrict__ targets,
    const float* __restrict__ feats, float* __restrict__ tlogit)
{
    int lane = threadIdx.x & 63;
    int wid  = threadIdx.x >> 6;
    int row  = blockIdx.x * 4 + wid;
    int tgt  = targets[row];
    const float4* a = (const float4*)(inputs + (size_t)row * NFEAT);
    const float4* f = (const float4*)(feats  + (size_t)tgt * NFEAT);
    float4 av = a[lane];
    float4 fv = f[lane];
    float d = av.x * fv.x + av.y * fv.y + av.z * fv.z + av.w * fv.w;
    #pragma unroll
    for (int off = 1; off < 64; off <<= 1)
        d += __shfl_xor(d, off, 64);
    if (lane == 0) tlogit[row] = d * TEMP_INV;
}

// ---------------------------------------------------------------------------
// Kernel 2: bf16 MFMA GEMM (global_load_lds staging, XOR-swizzled LDS) +
// per-chunk online-softmax partials. 128x128 tile, BK=64, 4 waves.
// LDS row = 64 bf16 = 8 chunks of 16B. Chunk kc of row r stored at
// position p = kc ^ (r&7)  => ds_read_b128 spreads over all 8 bank groups.
// ---------------------------------------------------------------------------
__global__ __launch_bounds__(256) void gemm_softmax_kernel(
    const __bf16* __restrict__ A, const __bf16* __restrict__ B,
    float2* __restrict__ partials)
{
    int L  = blockIdx.x;
    int j  = L & 7;
    int t  = L >> 3;
    int mx = t & 7;
    int ny = (t >> 3) * 8 + j;
    if (ny >= NCH) return;
    int m0 = mx * BM;
    int n0 = ny * BN;

    __shared__ __bf16 Alds[BM][BK];
    __shared__ __bf16 Blds[BN][BK];
    __shared__ float2 red[2][BM];

    int tid  = threadIdx.x;
    int lane = tid & 63;
    int wid  = tid >> 6;
    int wm   = wid & 1;
    int wn   = wid >> 1;
    int lrow = lane & 15;
    int quad = lane >> 4;

    f32x4 acc[4][4] = {};

    // staging: wave wid covers rows wid*32..wid*32+31 of A and B,
    // 4 instrs each, 8 rows per instr. lane: rowoff = lane>>3, chunkpos p = lane&7.
    int rowoff = lane >> 3;
    int p      = lane & 7;
    int kc     = p ^ rowoff;        // global chunk for swizzled position p
    const __bf16* Ag = A + (size_t)(m0 + wid * 32 + rowoff) * NFEAT + kc * 8;
    const __bf16* Bg = B + (size_t)(n0 + wid * 32 + rowoff) * NFEAT + kc * 8;

    for (int k0 = 0; k0 < NFEAT; k0 += BK) {
        __syncthreads();   // previous iteration's LDS reads complete
        #pragma unroll
        for (int i = 0; i < 4; i++) {
            GLOAD_LDS16(Ag + k0 + i * 8 * NFEAT, &Alds[wid * 32 + i * 8][0]);
            GLOAD_LDS16(Bg + k0 + i * 8 * NFEAT, &Blds[wid * 32 + i * 8][0]);
        }
        __syncthreads();   // drains vmcnt -> tiles resident in LDS
        #pragma unroll
        for (int ks = 0; ks < 2; ks++) {
            bf16x8 af[4], bfr[4];
            #pragma unroll
            for (int mi = 0; mi < 4; mi++) {
                int R = wm * 64 + mi * 16 + lrow;
                af[mi] = *(bf16x8*)&Alds[R][((ks * 4 + quad) ^ (lrow & 7)) * 8];
            }
            #pragma unroll
            for (int ni = 0; ni < 4; ni++) {
                int R = wn * 64 + ni * 16 + lrow;
                bfr[ni] = *(bf16x8*)&Blds[R][((ks * 4 + quad) ^ (lrow & 7)) * 8];
            }
            #pragma unroll
            for (int mi = 0; mi < 4; mi++)
                #pragma unroll
                for (int ni = 0; ni < 4; ni++)
                    acc[mi][ni] = __builtin_amdgcn_mfma_f32_16x16x32_bf16(
                        af[mi], bfr[ni], acc[mi][ni], 0, 0, 0);
        }
    }

    // ---- epilogue: per-row (m, s) over this block's 128 columns ----
    // C layout: row = quad*4 + reg, col = lane&15 (within each 16x16 tile)
    int colbase = n0 + wn * 64 + lrow;
    bool ok0 = (colbase +  0) < NSAMP;
    bool ok1 = (colbase + 16) < NSAMP;
    bool ok2 = (colbase + 32) < NSAMP;
    bool ok3 = (colbase + 48) < NSAMP;
    #pragma unroll
    for (int mi = 0; mi < 4; mi++) {
        #pragma unroll
        for (int reg = 0; reg < 4; reg++) {
            float v0 = ok0 ? acc[mi][0][reg] * TEMP_INV : NEG_SENTINEL;
            float v1 = ok1 ? acc[mi][1][reg] * TEMP_INV : NEG_SENTINEL;
            float v2 = ok2 ? acc[mi][2][reg] * TEMP_INV : NEG_SENTINEL;
            float v3 = ok3 ? acc[mi][3][reg] * TEMP_INV : NEG_SENTINEL;
            float m = fmaxf(fmaxf(v0, v1), fmaxf(v2, v3));
            #pragma unroll
            for (int off = 1; off < 16; off <<= 1)
                m = fmaxf(m, __shfl_xor(m, off, 64));
            float s = __expf(v0 - m) + __expf(v1 - m) +
                      __expf(v2 - m) + __expf(v3 - m);
            #pragma unroll
            for (int off = 1; off < 16; off <<= 1)
                s += __shfl_xor(s, off, 64);
            if (lrow == 0)
                red[wn][wm * 64 + mi * 16 + quad * 4 + reg] = make_float2(m, s);
        }
    }
    __syncthreads();
    if (tid < BM) {
        float2 a = red[0][tid], b = red[1][tid];
        float nm = fmaxf(a.x, b.x);
        float s  = a.y * __expf(a.x - nm) + b.y * __expf(b.x - nm);
        partials[(size_t)ny * BATCH + (m0 + tid)] = make_float2(nm, s);
    }
}

// ---------------------------------------------------------------------------
// Kernel 3: combine per-chunk partials -> lse -> nll -> mean (atomicAdd).
// ---------------------------------------------------------------------------
__global__ __launch_bounds__(256) void reduce_kernel(
    const float2* __restrict__ partials, const float* __restrict__ tlogit,
    float* __restrict__ out)
{
    __shared__ float2 red2[8][32];
    int tid = threadIdx.x;
    int rl  = tid & 31;
    int sp  = tid >> 5;
    int row = blockIdx.x * 32 + rl;
    int cs  = sp * 98;
    int ce  = cs + 98 < NCH ? cs + 98 : NCH;
    float m = NEG_SENTINEL, s = 0.f;
    #pragma unroll 4
    for (int c = cs; c < ce; c++) {
        float2 pt = partials[(size_t)c * BATCH + row];
        float nm = fmaxf(m, pt.x);
        s = s * __expf(m - nm) + pt.y * __expf(pt.x - nm);
        m = nm;
    }
    red2[sp][rl] = make_float2(m, s);
    __syncthreads();
    if (tid < 32) {
        float2 a = red2[0][rl];
        float M = a.x, S = a.y;
        #pragma unroll
        for (int q = 1; q < 8; q++) {
            float2 b = red2[q][rl];
            float nm = fmaxf(M, b.x);
            S = S * __expf(M - nm) + b.y * __expf(b.x - nm);
            M = nm;
        }
        float nll = (M + logf(S)) - tlogit[row];
        #pragma unroll
        for (int off = 1; off < 32; off <<= 1)
            nll += __shfl_xor(nll, off, 64);
        if (rl == 0) atomicAdd(out, nll * (1.0f / BATCH));
    }
}

// ---------------------------------------------------------------------------
extern "C" void kernel_launch(void* const* d_in, const int* in_sizes, int n_in,
                              void* d_out, int out_size, void* d_ws, size_t ws_size,
                              hipStream_t stream) {
    const float* inputs  = (const float*)d_in[0];
    const int*   targets = (const int*)d_in[1];
    const float* feats   = (const float*)d_in[2];
    float* out = (float*)d_out;

    // ws layout (bytes):
    //   fb       : 0                      .. 51,249,152   (100096*256 bf16)
    //   ib       : 51,249,152             .. 51,773,440   (1024*256 bf16)
    //   partials : 51,773,440             .. 58,179,584   (782*1024 float2)
    //   tlogit   : 58,179,584             .. +4096
    __bf16* fb       = (__bf16*)d_ws;
    __bf16* ib       = (__bf16*)((char*)d_ws + 51249152);
    float2* partials = (float2*)((char*)d_ws + 51773440);
    float*  tlogit   = (float*)((char*)d_ws + 58179584);

    hipMemsetAsync(out, 0, sizeof(float), stream);
    convert_kernel<<<CVT_UNITS / 256, 256, 0, stream>>>(feats, inputs, fb, ib);
    target_kernel<<<BATCH / 4, 256, 0, stream>>>(inputs, targets, feats, tlogit);
    gemm_softmax_kernel<<<8 * NCH_PAD, 256, 0, stream>>>(ib, fb, partials);
    reduce_kernel<<<BATCH / 32, 256, 0, stream>>>(partials, tlogit, out);
}